// Round 9
// baseline (535.377 us; speedup 1.0000x reference)
//
#include <hip/hip_runtime.h>
#include <hip/hip_bf16.h>

#define NN 100000
#define NE 1600000
#define D  128
#define SCAN_CHUNK 1024
#define NSCAN ((NN + SCAN_CHUNK - 1) / SCAN_CHUNK)   // 98
#define NB 98          // dst buckets of 1024 nodes (dst>>10)
#define BCHUNK 8192    // edges per bin_scatter block

typedef short bf16x8 __attribute__((ext_vector_type(8)));
typedef float f32x4 __attribute__((ext_vector_type(4)));

static __device__ inline unsigned short f2b(float f) {
    __hip_bfloat16 b = __float2bfloat16(f);   // RNE
    unsigned short u;
    __builtin_memcpy(&u, &b, 2);
    return u;
}

// coarse bucket histogram: 98 buckets, LDS-aggregated, ~19K global atomics total
__global__ __launch_bounds__(256) void bucket_count(const int* __restrict__ ei,
                                                    int* __restrict__ bcnt) {
    __shared__ int hist[NB];
    int chunk0 = blockIdx.x * BCHUNK;
    for (int t = threadIdx.x; t < NB; t += 256) hist[t] = 0;
    __syncthreads();
    for (int i = 0; i < BCHUNK; i += 256) {
        int e = chunk0 + i + threadIdx.x;
        if (e < NE) atomicAdd(&hist[ei[NE + e] >> 10], 1);
    }
    __syncthreads();
    for (int t = threadIdx.x; t < NB; t += 256)
        if (hist[t]) atomicAdd(&bcnt[t], hist[t]);
}

// per-node counts from bucket-grouped edges (cache-localized atomics)
__global__ void hist2(const unsigned long long* __restrict__ ebuf,
                      int* __restrict__ cnt) {
    int e = blockIdx.x * 256 + threadIdx.x;
    if (e < NE) atomicAdd(&cnt[(int)(ebuf[e] >> 32)], 1);
}

// per-1024-chunk exclusive scan, emit chunk sums
__global__ void scanA(const int* __restrict__ cnt, int* __restrict__ rowptr,
                      int* __restrict__ bsum) {
    __shared__ int lds[256];
    int tid  = threadIdx.x;
    int base = blockIdx.x * SCAN_CHUNK + tid * 4;
    int v[4];
#pragma unroll
    for (int i = 0; i < 4; ++i) v[i] = (base + i < NN) ? cnt[base + i] : 0;
    int s = v[0] + v[1] + v[2] + v[3];
    lds[tid] = s;
    __syncthreads();
    for (int off = 1; off < 256; off <<= 1) {
        int t = (tid >= off) ? lds[tid - off] : 0;
        __syncthreads();
        lds[tid] += t;
        __syncthreads();
    }
    int excl = lds[tid] - s;
    if (tid == 255) bsum[blockIdx.x] = lds[255];
    int run = excl;
#pragma unroll
    for (int i = 0; i < 4; ++i) {
        if (base + i < NN) rowptr[base + i] = run;
        run += v[i];
    }
}

// parallel exclusive scan of <=128 entries in place; optional 2nd output copy
__global__ void scanB(int* __restrict__ a, int* __restrict__ out2, int nb) {
    __shared__ int s[128];
    int t = threadIdx.x;
    int v = (t < nb) ? a[t] : 0;
    s[t] = v;
    __syncthreads();
    for (int off = 1; off < 128; off <<= 1) {
        int tv = (t >= off) ? s[t - off] : 0;
        __syncthreads();
        s[t] += tv;
        __syncthreads();
    }
    if (t < nb) {
        int excl = s[t] - v;
        a[t] = excl;
        if (out2) out2[t] = excl;
    }
}

// finalize rowptr; produce fill cursor (copy)
__global__ void scanC(int* __restrict__ rowptr, const int* __restrict__ bsum,
                      int* __restrict__ cursor) {
    int i = blockIdx.x * 256 + threadIdx.x;
    if (i < NN) {
        int v = rowptr[i] + bsum[i / SCAN_CHUNK];
        rowptr[i] = v;
        cursor[i] = v;
    }
    if (i == 0) rowptr[NN] = NE;
}

// Phase B: bin edges by dst>>10 into bucket-grouped (dst,src) pairs.
__global__ __launch_bounds__(256) void bin_scatter(const int* __restrict__ ei,
                                                   int* __restrict__ gcur,
                                                   unsigned long long* __restrict__ ebuf) {
    __shared__ int hist[NB];
    __shared__ int base_s[NB];
    int chunk0 = blockIdx.x * BCHUNK;
    for (int t = threadIdx.x; t < NB; t += 256) hist[t] = 0;
    __syncthreads();
    for (int i = 0; i < BCHUNK; i += 256) {
        int e = chunk0 + i + threadIdx.x;
        if (e < NE) atomicAdd(&hist[ei[NE + e] >> 10], 1);
    }
    __syncthreads();
    for (int t = threadIdx.x; t < NB; t += 256) {
        base_s[t] = atomicAdd(&gcur[t], hist[t]);
        hist[t] = 0;
    }
    __syncthreads();
    for (int i = 0; i < BCHUNK; i += 256) {
        int e = chunk0 + i + threadIdx.x;
        if (e < NE) {
            int s = ei[e];
            int d = ei[NE + e];
            int b = d >> 10;
            int off = atomicAdd(&hist[b], 1);
            ebuf[(size_t)base_s[b] + off] =
                ((unsigned long long)(unsigned)d << 32) | (unsigned)s;
        }
    }
}

// Phase C: edges bucket-grouped; scatter src into CSR col (L2-resident window).
__global__ void fill_from_buckets(const unsigned long long* __restrict__ ebuf,
                                  int* __restrict__ cursor, int* __restrict__ col) {
    int e = blockIdx.x * 256 + threadIdx.x;
    if (e < NE) {
        unsigned long long p = ebuf[e];
        int s = (int)(p & 0xffffffffu);
        int d = (int)(p >> 32);
        int pos = atomicAdd(&cursor[d], 1);
        col[pos] = s;
    }
}

// fp32 -> bf16 conversion, 4 elems/thread
__global__ void conv_f2b(const float* __restrict__ src,
                         unsigned short* __restrict__ dst, int n) {
    int i = (blockIdx.x * 256 + threadIdx.x) * 4;
    if (i + 3 < n) {
        float4 v = *(const float4*)(src + i);
        ushort4 o;
        o.x = f2b(v.x); o.y = f2b(v.y); o.z = f2b(v.z); o.w = f2b(v.w);
        *(ushort4*)(dst + i) = o;
    } else {
        for (; i < n; ++i) dst[i] = f2b(src[i]);
    }
}

// all 4 weight matrices (each D*D) in one launch; dsts contiguous
__global__ void conv_w4(const float* __restrict__ s0, const float* __restrict__ s1,
                        const float* __restrict__ s2, const float* __restrict__ s3,
                        unsigned short* __restrict__ dst) {
    int i = (blockIdx.x * 256 + threadIdx.x) * 4;   // [0, 4*D*D)
    const float* srcs[4] = {s0, s1, s2, s3};
    const float* s = srcs[i >> 14];                 // D*D = 16384
    float4 v = *(const float4*)(s + (i & 16383));
    ushort4 o;
    o.x = f2b(v.x); o.y = f2b(v.y); o.z = f2b(v.z); o.w = f2b(v.w);
    *(ushort4*)(dst + i) = o;
}

// Channel-sliced XCD-pinned mean aggregation.
// bid&7 -> XCD (round-robin heuristic). Channel group g = (bid&7)>>1 owns
// channels [g*32, g*32+32) (one aligned 64B line per row). Each XCD pair
// covers all nodes for its group; per-XCD gather working set = 100K x 64B
// = 6.4 MB (~L2-sized) instead of 100K x 256B duplicated 8 ways.
// Wave: 1 node; 8 edges in flight (e8 = lane>>3) x 8 lanes x uint2 (64B/edge).
__global__ __launch_bounds__(256) void aggregate_slice(
    const unsigned short* __restrict__ hb,
    const int* __restrict__ rowptr,
    const int* __restrict__ col,
    unsigned short* __restrict__ aggb)
{
    int bid = blockIdx.x;
    int g   = (bid & 7) >> 1;          // channel group 0..3
    int par = bid & 1;                 // node half
    int u   = bid >> 3;                // 0..12499
    int node = par * (NN / 2) + u * 4 + (threadIdx.x >> 6);
    int lane = threadIdx.x & 63;
    int e8 = lane >> 3;                // edge slot 0..7
    int c  = lane & 7;                 // uint2 index within 64B slice

    int beg = rowptr[node], end = rowptr[node + 1];
    const uint2* hp = (const uint2*)hb;          // 32 uint2 per row
    const int slice = g * 8 + c;
    float a0 = 0.f, a1 = 0.f, a2 = 0.f, a3 = 0.f;

    for (int j = beg + e8; j < end; j += 8) {
        int s = col[j];
        uint2 v = hp[s * 32 + slice];
        a0 += __uint_as_float(v.x << 16);
        a1 += __uint_as_float(v.x & 0xffff0000u);
        a2 += __uint_as_float(v.y << 16);
        a3 += __uint_as_float(v.y & 0xffff0000u);
    }

#pragma unroll
    for (int off = 8; off < 64; off <<= 1) {
        a0 += __shfl_xor(a0, off);
        a1 += __shfl_xor(a1, off);
        a2 += __shfl_xor(a2, off);
        a3 += __shfl_xor(a3, off);
    }

    int deg = end - beg;
    float inv = 1.0f / (float)(deg > 1 ? deg : 1);
    if (e8 == 0) {
        uint2 o;
        o.x = (unsigned)f2b(a0 * inv) | ((unsigned)f2b(a1 * inv) << 16);
        o.y = (unsigned)f2b(a2 * inv) | ((unsigned)f2b(a3 * inv) << 16);
        ((uint2*)aggb)[(size_t)node * 32 + slice] = o;
    }
}

// out[n][j] = leaky_relu( sum_k agg[n][k]*Wl[j][k] + h[n][k]*Wr[j][k] + b[j], 0.5 )
// MFMA 16x16x32 bf16. Block = 256 thr = 4 waves (2x2), block tile 64 rows x 128 cols,
// wave tile 32 rows x 64 cols. No LDS, no barriers: fragments load direct from global.
template <int OUT_F32>
__global__ __launch_bounds__(256) void sage_gemm_mfma(
    const unsigned short* __restrict__ Ab,   // [NN][128] aggregated
    const unsigned short* __restrict__ Hb,   // [NN][128] root
    const unsigned short* __restrict__ Wlb,  // [128][128], row j contiguous in k
    const unsigned short* __restrict__ Wrb,
    const float* __restrict__ bias,
    float* __restrict__ outf,
    unsigned short* __restrict__ outb)
{
    const int lane = threadIdx.x & 63;
    const int wid  = threadIdx.x >> 6;
    const int r  = lane & 15;
    const int kg = lane >> 4;
    const int row0 = blockIdx.x * 64 + (wid >> 1) * 32;
    const int col0 = (wid & 1) * 64;

    const int ra0 = min(row0 + r,      NN - 1);
    const int ra1 = min(row0 + 16 + r, NN - 1);

    float bv[4];
#pragma unroll
    for (int c = 0; c < 4; ++c) bv[c] = bias[col0 + c * 16 + r];

    f32x4 acc[2][4];
#pragma unroll
    for (int m = 0; m < 2; ++m)
#pragma unroll
        for (int c = 0; c < 4; ++c) acc[m][c] = (f32x4){0.f, 0.f, 0.f, 0.f};

#pragma unroll
    for (int ks = 0; ks < 8; ++ks) {
        const unsigned short* S = (ks < 4) ? Ab : Hb;
        const unsigned short* W = (ks < 4) ? Wlb : Wrb;
        const int kk = (ks & 3) * 32 + kg * 8;
        bf16x8 a0 = *(const bf16x8*)(S + (size_t)ra0 * D + kk);
        bf16x8 a1 = *(const bf16x8*)(S + (size_t)ra1 * D + kk);
        bf16x8 bw[4];
#pragma unroll
        for (int c = 0; c < 4; ++c)
            bw[c] = *(const bf16x8*)(W + (size_t)(col0 + c * 16 + r) * D + kk);
#pragma unroll
        for (int c = 0; c < 4; ++c) {
            acc[0][c] = __builtin_amdgcn_mfma_f32_16x16x32_bf16(a0, bw[c], acc[0][c], 0, 0, 0);
            acc[1][c] = __builtin_amdgcn_mfma_f32_16x16x32_bf16(a1, bw[c], acc[1][c], 0, 0, 0);
        }
    }

    // C/D layout: col = c*16 + (lane&15), row = m*16 + (lane>>4)*4 + q   [m89]
#pragma unroll
    for (int m = 0; m < 2; ++m) {
#pragma unroll
        for (int q = 0; q < 4; ++q) {
            int row = row0 + m * 16 + kg * 4 + q;
            if (row < NN) {
#pragma unroll
                for (int c = 0; c < 4; ++c) {
                    float v = acc[m][c][q] + bv[c];
                    v = v > 0.f ? v : 0.5f * v;
                    int colj = col0 + c * 16 + r;
                    if (OUT_F32) outf[(size_t)row * D + colj] = v;
                    else         outb[(size_t)row * D + colj] = f2b(v);
                }
            }
        }
    }
}

extern "C" void kernel_launch(void* const* d_in, const int* in_sizes, int n_in,
                              void* d_out, int out_size, void* d_ws, size_t ws_size,
                              hipStream_t stream) {
    const float* x   = (const float*)d_in[0];
    const int*   ei  = (const int*)d_in[1];
    const float* W1l = (const float*)d_in[2];
    const float* W1r = (const float*)d_in[3];
    const float* b1  = (const float*)d_in[4];
    const float* W2l = (const float*)d_in[5];
    const float* W2r = (const float*)d_in[6];
    const float* b2  = (const float*)d_in[7];
    float* out = (float*)d_out;

    char* ws = (char*)d_ws;
    size_t off = 0;
    auto alloc = [&](size_t bytes) {
        void* p = ws + off;
        off = (off + bytes + 255) & ~(size_t)255;
        return p;
    };
    int* rowptr = (int*)alloc((NN + 1) * 4);
    int* cursor = (int*)alloc(NN * 4);          // doubles as per-node cnt
    int* bsum   = (int*)alloc(4096);
    int* bcnt   = (int*)alloc(512);
    int* gcur   = (int*)alloc(512);
    int* col    = (int*)alloc((size_t)NE * 4);
    unsigned short* xb   = (unsigned short*)alloc((size_t)NN * D * 2);
    unsigned short* aggb = (unsigned short*)alloc((size_t)NN * D * 2);
    unsigned short* h1b  = (unsigned short*)alloc((size_t)NN * D * 2);
    unsigned short* wb   = (unsigned short*)alloc((size_t)4 * D * D * 2);
    unsigned short* w1lb = wb;
    unsigned short* w1rb = wb + D * D;
    unsigned short* w2lb = wb + 2 * D * D;
    unsigned short* w2rb = wb + 3 * D * D;
    // ebuf (12.8 MB) aliases h1b (25.6 MB): ebuf dead before h1b is written
    unsigned long long* ebuf = (unsigned long long*)h1b;

    // ---- CSR build (no random per-node atomics anywhere) ----
    hipMemsetAsync(cursor, 0, (size_t)NN * 4, stream);
    hipMemsetAsync(bcnt, 0, NB * 4, stream);
    bucket_count<<<(NE + BCHUNK - 1) / BCHUNK, 256, 0, stream>>>(ei, bcnt);
    scanB<<<1, 128, 0, stream>>>(bcnt, gcur, NB);
    bin_scatter<<<(NE + BCHUNK - 1) / BCHUNK, 256, 0, stream>>>(ei, gcur, ebuf);
    hist2<<<(NE + 255) / 256, 256, 0, stream>>>(ebuf, cursor);
    scanA<<<NSCAN, 256, 0, stream>>>(cursor, rowptr, bsum);
    scanB<<<1, 128, 0, stream>>>(bsum, nullptr, NSCAN);
    scanC<<<(NN + 255) / 256, 256, 0, stream>>>(rowptr, bsum, cursor);
    fill_from_buckets<<<(NE + 255) / 256, 256, 0, stream>>>(ebuf, cursor, col);

    // ---- bf16 conversions ----
    conv_f2b<<<(NN * D / 4 + 255) / 256, 256, 0, stream>>>(x, xb, NN * D);
    conv_w4<<<(4 * D * D / 4 + 255) / 256, 256, 0, stream>>>(W1l, W1r, W2l, W2r, wb);

    // ---- layer 1 ----
    aggregate_slice<<<(NN / 2) * 2, 256, 0, stream>>>(xb, rowptr, col, aggb);
    sage_gemm_mfma<0><<<(NN + 63) / 64, 256, 0, stream>>>(aggb, xb, w1lb, w1rb, b1,
                                                          nullptr, h1b);
    // ---- layer 2 ----
    aggregate_slice<<<(NN / 2) * 2, 256, 0, stream>>>(h1b, rowptr, col, aggb);
    sage_gemm_mfma<1><<<(NN + 63) / 64, 256, 0, stream>>>(aggb, h1b, w2lb, w2rb, b2,
                                                          out, nullptr);
}